// Round 1
// baseline (718.302 us; speedup 1.0000x reference)
//
#include <hip/hip_runtime.h>
#include <hip/hip_bf16.h>

#define E_TOTAL   1600000
#define NV        50000
#define DE        64
#define DV        64
#define DIN       192
#define DHID      128
#define DOUT      64
#define TILE_M    64
#define XS        200          // xb row stride (ushorts), padded from 192
#define HS        136          // hb row stride (ushorts), padded from 128
#define NTILES    (E_TOTAL / TILE_M)   // 25000 exact

typedef __bf16 bf16x8 __attribute__((ext_vector_type(8)));
typedef float  floatx4 __attribute__((ext_vector_type(4)));
typedef float  fx4     __attribute__((ext_vector_type(4)));

static __device__ __forceinline__ unsigned short f2bf(float f) {
    unsigned int u = __float_as_uint(f);
    u += 0x7fffu + ((u >> 16) & 1u);   // round-to-nearest-even
    return (unsigned short)(u >> 16);
}

// ---- prep: W1 [192][128] -> w1t bf16 [128][192]; W2 [128][64] -> w2t bf16 [64][128];
//      vfeat fp32 [NV][64] -> vfb bf16 (same layout)
__global__ void prep_kernel(const float* __restrict__ W1, const float* __restrict__ W2,
                            const float* __restrict__ vfeat,
                            unsigned short* __restrict__ w1t,
                            unsigned short* __restrict__ w2t,
                            unsigned short* __restrict__ vfb, int do_vfb) {
    int tid = blockIdx.x * blockDim.x + threadIdx.x;
    int stride = gridDim.x * blockDim.x;
    for (int i = tid; i < DIN * DHID; i += stride) {
        int n = i / DIN, k = i % DIN;
        w1t[i] = f2bf(W1[k * DHID + n]);
    }
    for (int i = tid; i < DHID * DOUT; i += stride) {
        int n = i / DHID, k = i % DHID;
        w2t[i] = f2bf(W2[k * DOUT + n]);
    }
    if (do_vfb) {
        const fx4* src = (const fx4*)vfeat;
        ushort4* dst = (ushort4*)vfb;
        int n4 = NV * DV / 4;
        for (int i = tid; i < n4; i += stride) {
            fx4 v = src[i];
            ushort4 o;
            o.x = f2bf(v[0]); o.y = f2bf(v[1]); o.z = f2bf(v[2]); o.w = f2bf(v[3]);
            dst[i] = o;
        }
    }
}

template <bool USE_VFB>
__global__ __launch_bounds__(256, 2) void edge_mlp(
    const float* __restrict__ edata,
    const float* __restrict__ vfeat,
    const float* __restrict__ b1,
    const float* __restrict__ b2,
    const int* __restrict__ senders,
    const int* __restrict__ receivers,
    const unsigned short* __restrict__ w1t,
    const unsigned short* __restrict__ w2t,
    const unsigned short* __restrict__ vfb,
    float* __restrict__ out) {
    __shared__ unsigned short xb[TILE_M * XS];   // 25600 B
    __shared__ unsigned short hb[TILE_M * HS];   // 17408 B

    const int tid  = threadIdx.x;
    const int lane = tid & 63;
    const int wave = tid >> 6;
    const int l15  = lane & 15;
    const int quad = lane >> 4;

    // ---- per-wave weight fragments in registers (one-time; grid-stride loop amortizes)
    bf16x8 w1f[6][2];   // [k-step][n-block], this wave's N-slice = cols wave*32 .. wave*32+31
    bf16x8 w2f[4];      // this wave's N-slice = cols wave*16 .. wave*16+15
    {
        for (int nb = 0; nb < 2; ++nb) {
            int n = wave * 32 + nb * 16 + l15;
            const unsigned short* p = w1t + n * DIN + quad * 8;
            for (int ks = 0; ks < 6; ++ks)
                w1f[ks][nb] = *(const bf16x8*)(p + ks * 32);
        }
        int n2 = wave * 16 + l15;
        const unsigned short* p2 = w2t + n2 * DHID + quad * 8;
        for (int ks = 0; ks < 4; ++ks)
            w2f[ks] = *(const bf16x8*)(p2 + ks * 32);
    }
    const float bias1a = b1[wave * 32 + l15];
    const float bias1b = b1[wave * 32 + 16 + l15];
    const float bias2  = b2[wave * 16 + l15];

    for (int t = blockIdx.x; t < NTILES; t += gridDim.x) {
        const int e0 = t * TILE_M;

        // ---- stage x tile: [64 edges][192 bf16] = edata | vfeat[recv] | vfeat[send]
        {
            // edata: 64 edges x 16 float4
#pragma unroll
            for (int it = 0; it < 4; ++it) {
                int idx = it * 256 + tid;
                int e = idx >> 4;
                int c = idx & 15;
                fx4 v = __builtin_nontemporal_load((const fx4*)(edata + (e0 + e) * DE + c * 4));
                ushort4 o;
                o.x = f2bf(v[0]); o.y = f2bf(v[1]); o.z = f2bf(v[2]); o.w = f2bf(v[3]);
                *(ushort4*)(xb + e * XS + c * 4) = o;
            }
            if constexpr (USE_VFB) {
                // bf16 vertex table: 64 edges x 2 gathers x 8 chunks of 16B
#pragma unroll
                for (int it = 0; it < 4; ++it) {
                    int idx = it * 256 + tid;
                    int e = idx >> 4;
                    int g = (idx >> 3) & 1;
                    int c = idx & 7;
                    int row = g ? senders[e0 + e] : receivers[e0 + e];
                    uint4 v = *(const uint4*)(vfb + row * DV + c * 8);
                    *(uint4*)(xb + e * XS + DE + g * DV + c * 8) = v;
                }
            } else {
                // fp32 vertex table fallback
#pragma unroll
                for (int it = 0; it < 8; ++it) {
                    int idx = it * 256 + tid;
                    int e = idx >> 5;
                    int g = (idx >> 4) & 1;
                    int c = idx & 15;
                    int row = g ? senders[e0 + e] : receivers[e0 + e];
                    fx4 v = *(const fx4*)(vfeat + row * DV + c * 4);
                    ushort4 o;
                    o.x = f2bf(v[0]); o.y = f2bf(v[1]); o.z = f2bf(v[2]); o.w = f2bf(v[3]);
                    *(ushort4*)(xb + e * XS + DE + g * DV + c * 4) = o;
                }
            }
        }
        __syncthreads();

        // ---- layer 1: h[64][128] = relu(x @ W1 + b1); each wave does N-slice of 32
        floatx4 acc[4][2];
#pragma unroll
        for (int mb = 0; mb < 4; ++mb) {
            acc[mb][0] = (floatx4){bias1a, bias1a, bias1a, bias1a};
            acc[mb][1] = (floatx4){bias1b, bias1b, bias1b, bias1b};
        }
#pragma unroll
        for (int ks = 0; ks < 6; ++ks) {
            bf16x8 a[4];
#pragma unroll
            for (int mb = 0; mb < 4; ++mb)
                a[mb] = *(const bf16x8*)(xb + (mb * 16 + l15) * XS + ks * 32 + quad * 8);
#pragma unroll
            for (int mb = 0; mb < 4; ++mb)
#pragma unroll
                for (int nb = 0; nb < 2; ++nb)
                    acc[mb][nb] = __builtin_amdgcn_mfma_f32_16x16x32_bf16(
                        a[mb], w1f[ks][nb], acc[mb][nb], 0, 0, 0);
        }
        // relu + write h to LDS as bf16. C layout: col=lane&15, row=quad*4+r
#pragma unroll
        for (int mb = 0; mb < 4; ++mb) {
            int rowm = mb * 16 + quad * 4;
#pragma unroll
            for (int nb = 0; nb < 2; ++nb) {
                int col = wave * 32 + nb * 16 + l15;
#pragma unroll
                for (int r = 0; r < 4; ++r) {
                    float v = acc[mb][nb][r];
                    v = v > 0.f ? v : 0.f;
                    hb[(rowm + r) * HS + col] = f2bf(v);
                }
            }
        }
        __syncthreads();

        // ---- layer 2: out[64][64] = h @ W2 + b2; each wave does N-slice of 16
        floatx4 acc2[4];
#pragma unroll
        for (int mb = 0; mb < 4; ++mb)
            acc2[mb] = (floatx4){bias2, bias2, bias2, bias2};
#pragma unroll
        for (int ks = 0; ks < 4; ++ks)
#pragma unroll
            for (int mb = 0; mb < 4; ++mb) {
                bf16x8 a2 = *(const bf16x8*)(hb + (mb * 16 + l15) * HS + ks * 32 + quad * 8);
                acc2[mb] = __builtin_amdgcn_mfma_f32_16x16x32_bf16(a2, w2f[ks], acc2[mb], 0, 0, 0);
            }
        // store (nontemporal: streaming writes, keep L2 for vfeat gathers)
#pragma unroll
        for (int mb = 0; mb < 4; ++mb) {
            int rowm = mb * 16 + quad * 4;
            int col = wave * 16 + l15;
#pragma unroll
            for (int r = 0; r < 4; ++r)
                __builtin_nontemporal_store(acc2[mb][r], out + (e0 + rowm + r) * DOUT + col);
        }
        __syncthreads();  // xb reuse guard for next tile's staging vs this tile's hb readers is
                          // covered by next B1; this barrier protects hb vs next L1 writers? No:
                          // actually 2 barriers suffice logically, but keep this one until profiled.
    }
}

extern "C" void kernel_launch(void* const* d_in, const int* in_sizes, int n_in,
                              void* d_out, int out_size, void* d_ws, size_t ws_size,
                              hipStream_t stream) {
    const float* edata     = (const float*)d_in[0];
    const float* vfeat     = (const float*)d_in[1];
    const float* W1        = (const float*)d_in[2];
    const float* b1        = (const float*)d_in[3];
    const float* W2        = (const float*)d_in[4];
    const float* b2        = (const float*)d_in[5];
    const int*   senders   = (const int*)d_in[6];
    const int*   receivers = (const int*)d_in[7];
    float* out = (float*)d_out;

    unsigned short* w1t = (unsigned short*)d_ws;
    unsigned short* w2t = w1t + DIN * DHID;
    unsigned short* vfb = w2t + DHID * DOUT;
    const size_t need_vfb = (size_t)(DIN * DHID + DHID * DOUT + NV * DV) * sizeof(unsigned short);
    const bool use_vfb = ws_size >= need_vfb;

    prep_kernel<<<512, 256, 0, stream>>>(W1, W2, vfeat, w1t, w2t, vfb, use_vfb ? 1 : 0);
    if (use_vfb)
        edge_mlp<true><<<1536, 256, 0, stream>>>(edata, vfeat, b1, b2, senders, receivers,
                                                 w1t, w2t, vfb, out);
    else
        edge_mlp<false><<<1536, 256, 0, stream>>>(edata, vfeat, b1, b2, senders, receivers,
                                                  w1t, w2t, vfb, out);
}